// Round 2
// baseline (86.797 us; speedup 1.0000x reference)
//
#include <hip/hip_runtime.h>
#include <hip/hip_bf16.h>

// ---------------- problem constants ----------------
#define S_LEN 4096
#define IN_DIM 768
#define D_DIM 512
#define N_HEADS 8
#define H_DIM 64
#define TSE_DIM 1536   // 3*DIM

typedef __attribute__((ext_vector_type(8))) short frag8;   // 8 bf16 = 4 VGPRs
typedef __attribute__((ext_vector_type(4))) float f32x4;

__device__ __forceinline__ unsigned short f2bfbits(float f) {
    // round-to-nearest-even bf16 (no NaN handling needed for this workload)
    unsigned int u = __float_as_uint(f);
    unsigned int r = (u + 0x7FFFu + ((u >> 16) & 1u)) >> 16;
    return (unsigned short)r;
}

// ---------------- fp32 -> bf16 elementwise (x) ----------------
__global__ __launch_bounds__(256) void cvt_f32_bf16_v4(
        const float4* __restrict__ in, ushort4* __restrict__ out, int n4) {
    int i = blockIdx.x * 256 + threadIdx.x;
    if (i < n4) {
        float4 v = in[i];
        ushort4 o;
        o.x = f2bfbits(v.x); o.y = f2bfbits(v.y);
        o.z = f2bfbits(v.z); o.w = f2bfbits(v.w);
        out[i] = o;
    }
}

// ---------------- fp32 W[K][N] -> bf16 Wt[N][K] (convert + transpose) ----------------
__global__ __launch_bounds__(256) void transcvt(
        const float* __restrict__ in, unsigned short* __restrict__ out, int K, int N) {
    __shared__ float tile[32][33];
    int kb = blockIdx.x * 32, nb = blockIdx.y * 32;
    int tx = threadIdx.x & 31, ty = threadIdx.x >> 5;   // ty: 0..7
    #pragma unroll
    for (int r = ty; r < 32; r += 8)
        tile[r][tx] = in[(size_t)(kb + r) * N + nb + tx];
    __syncthreads();
    #pragma unroll
    for (int r = ty; r < 32; r += 8)
        out[(size_t)(nb + r) * K + kb + tx] = f2bfbits(tile[tx][r]);
}

// ---------------- bf16 NT-GEMM: C[M][N] = A[M][K] * Bt[N][K]^T (+bias) ----------------
// Tile 128x64, BK=32, 4 waves (2x2), each wave 64x32 = 4x2 frags of 16x16x32.
template<bool OUT_BF16, bool BIAS>
__global__ __launch_bounds__(256) void gemm_nt(
        const unsigned short* __restrict__ A,
        const unsigned short* __restrict__ Bt,
        const float* __restrict__ bias,
        void* __restrict__ C,
        int M, int N, int K) {
    constexpr int LDT = 56;  // padded LDS stride (112 B: 16B-aligned, ~2-way conflicts)
    __shared__ __align__(16) short As[128][LDT];
    __shared__ __align__(16) short Bs[64][LDT];

    const int bm = blockIdx.x * 128;
    const int bn = blockIdx.y * 64;
    const int tid = threadIdx.x;
    const int lane = tid & 63;
    const int wave = tid >> 6;
    const int wr = wave >> 1;          // 0..1 (64 rows each)
    const int wc = wave & 1;           // 0..1 (32 cols each)
    const int fr = lane & 15;          // 16-index within fragment
    const int fg = lane >> 4;          // k-group 0..3

    f32x4 acc[4][2];
    #pragma unroll
    for (int mi = 0; mi < 4; ++mi)
        #pragma unroll
        for (int ni = 0; ni < 2; ++ni)
            acc[mi][ni] = (f32x4)(0.f);

    const int kTiles = K >> 5;
    for (int kt = 0; kt < kTiles; ++kt) {
        const int k0 = kt << 5;
        // stage A: 128 rows x 32 bf16 = 512 chunks of 16B, 2 per thread
        #pragma unroll
        for (int rep = 0; rep < 2; ++rep) {
            int idx = rep * 256 + tid;
            int row = idx >> 2, ch = idx & 3;
            frag8 v = *(const frag8*)(A + (size_t)(bm + row) * K + k0 + ch * 8);
            *(frag8*)&As[row][ch * 8] = v;
        }
        // stage B: 64 rows x 32 bf16 = 256 chunks, 1 per thread
        {
            int row = tid >> 2, ch = tid & 3;
            frag8 v = *(const frag8*)(Bt + (size_t)(bn + row) * K + k0 + ch * 8);
            *(frag8*)&Bs[row][ch * 8] = v;
        }
        __syncthreads();

        frag8 a[4], b[2];
        #pragma unroll
        for (int mi = 0; mi < 4; ++mi)
            a[mi] = *(const frag8*)&As[wr * 64 + mi * 16 + fr][fg * 8];
        #pragma unroll
        for (int ni = 0; ni < 2; ++ni)
            b[ni] = *(const frag8*)&Bs[wc * 32 + ni * 16 + fr][fg * 8];

        #pragma unroll
        for (int mi = 0; mi < 4; ++mi)
            #pragma unroll
            for (int ni = 0; ni < 2; ++ni)
                acc[mi][ni] = __builtin_amdgcn_mfma_f32_16x16x32_bf16(
                        a[mi], b[ni], acc[mi][ni], 0, 0, 0);
        __syncthreads();
    }

    // epilogue: C/D layout col=lane&15, row=(lane>>4)*4+reg  [HW-verified m89/m91]
    #pragma unroll
    for (int mi = 0; mi < 4; ++mi) {
        int grow = bm + wr * 64 + mi * 16 + fg * 4;
        #pragma unroll
        for (int ni = 0; ni < 2; ++ni) {
            int gcol = bn + wc * 32 + ni * 16 + fr;
            float bv = BIAS ? bias[gcol] : 0.f;
            #pragma unroll
            for (int r = 0; r < 4; ++r) {
                float v = acc[mi][ni][r] + bv;
                if (OUT_BF16)
                    ((unsigned short*)C)[(size_t)(grow + r) * N + gcol] = f2bfbits(v);
                else
                    ((float*)C)[(size_t)(grow + r) * N + gcol] = v;
            }
        }
    }
}

// ---------------- dilated attention: one wave per (s, head) ----------------
// tse fp32: row s = [q(512) | k(512) | v(512)], head h at offset h*64.
__global__ __launch_bounds__(256) void attn_kernel(
        const float* __restrict__ tse, unsigned short* __restrict__ out) {
    const int wave = threadIdx.x >> 6;
    const int lane = threadIdx.x & 63;          // = head dim index d
    const int pair = blockIdx.x * 4 + wave;     // 0 .. 32767
    const int s = pair >> 3;
    const int h = pair & 7;

    const float qd = tse[(size_t)s * TSE_DIM + h * H_DIM + lane];
    const float scale = 0.125f;  // 64^-0.5

    float sc[7];
    #pragma unroll
    for (int j = 0; j < 7; ++j) {
        int t = s + (j - 3) * 8;
        bool valid = (t >= 0) && (t < S_LEN);
        float p = 0.f;
        if (valid) {
            float kd = tse[(size_t)t * TSE_DIM + D_DIM + h * H_DIM + lane];
            p = qd * kd;
        }
        #pragma unroll
        for (int off = 32; off; off >>= 1) p += __shfl_xor(p, off, 64);
        sc[j] = valid ? p * scale : -__builtin_inff();
    }

    float m = sc[0];
    #pragma unroll
    for (int j = 1; j < 7; ++j) m = fmaxf(m, sc[j]);

    float denom = 0.f, o = 0.f;
    #pragma unroll
    for (int j = 0; j < 7; ++j) {
        int t = s + (j - 3) * 8;
        bool valid = (t >= 0) && (t < S_LEN);
        float p = valid ? __expf(sc[j] - m) : 0.f;
        denom += p;
        if (valid) {
            float vd = tse[(size_t)t * TSE_DIM + 2 * D_DIM + h * H_DIM + lane];
            o += p * vd;
        }
    }
    out[(size_t)s * D_DIM + h * H_DIM + lane] = f2bfbits(o / denom);
}

// ---------------- launch ----------------
extern "C" void kernel_launch(void* const* d_in, const int* in_sizes, int n_in,
                              void* d_out, int out_size, void* d_ws, size_t ws_size,
                              hipStream_t stream) {
    (void)in_sizes; (void)n_in; (void)out_size;
    const float* x     = (const float*)d_in[0];
    const float* W_in  = (const float*)d_in[1];
    const float* b_in  = (const float*)d_in[2];
    const float* W_tse = (const float*)d_in[3];
    const float* W_out = (const float*)d_in[4];
    const float* b_out = (const float*)d_in[5];

    char* p = (char*)d_ws;
    unsigned short* xb    = (unsigned short*)p; p += (size_t)S_LEN * IN_DIM * 2;
    unsigned short* WinT  = (unsigned short*)p; p += (size_t)D_DIM * IN_DIM * 2;
    unsigned short* WtseT = (unsigned short*)p; p += (size_t)TSE_DIM * D_DIM * 2;
    unsigned short* WoutT = (unsigned short*)p; p += (size_t)D_DIM * D_DIM * 2;
    unsigned short* h     = (unsigned short*)p; p += (size_t)S_LEN * D_DIM * 2;
    float*          tse   = (float*)p;          p += (size_t)S_LEN * TSE_DIM * 4;
    unsigned short* attn  = (unsigned short*)p; p += (size_t)S_LEN * D_DIM * 2;
    if ((size_t)(p - (char*)d_ws) > ws_size) return;  // loud failure if ws too small

    // conversions
    cvt_f32_bf16_v4<<<(S_LEN * IN_DIM / 4 + 255) / 256, 256, 0, stream>>>(
            (const float4*)x, (ushort4*)xb, S_LEN * IN_DIM / 4);
    transcvt<<<dim3(IN_DIM / 32, D_DIM / 32), 256, 0, stream>>>(W_in, WinT, IN_DIM, D_DIM);
    transcvt<<<dim3(D_DIM / 32, TSE_DIM / 32), 256, 0, stream>>>(W_tse, WtseT, D_DIM, TSE_DIM);
    transcvt<<<dim3(D_DIM / 32, D_DIM / 32), 256, 0, stream>>>(W_out, WoutT, D_DIM, D_DIM);

    // h = x @ W_in + b_in   (bf16 out)
    gemm_nt<true, true><<<dim3(S_LEN / 128, D_DIM / 64), 256, 0, stream>>>(
            xb, WinT, b_in, h, S_LEN, D_DIM, IN_DIM);
    // tse = h @ W_tse       (fp32 out, no bias)
    gemm_nt<false, false><<<dim3(S_LEN / 128, TSE_DIM / 64), 256, 0, stream>>>(
            h, WtseT, nullptr, tse, S_LEN, TSE_DIM, D_DIM);
    // dilated attention     (bf16 out)
    attn_kernel<<<S_LEN * N_HEADS / 4, 256, 0, stream>>>(tse, attn);
    // out = attn @ W_out + b_out  (fp32 out -> d_out, reference output is float32)
    gemm_nt<false, true><<<dim3(S_LEN / 128, D_DIM / 64), 256, 0, stream>>>(
            attn, WoutT, b_out, (float*)d_out, S_LEN, D_DIM, D_DIM);
}

// Round 3
// 86.477 us; speedup vs baseline: 1.0037x; 1.0037x over previous
//
#include <hip/hip_runtime.h>
#include <hip/hip_bf16.h>

// ---------------- problem constants ----------------
#define S_LEN 4096
#define IN_DIM 768
#define D_DIM 512
#define N_HEADS 8
#define H_DIM 64
#define TSE_DIM 1536   // 3*DIM

typedef __attribute__((ext_vector_type(8))) short frag8;   // 8 bf16 = 4 VGPRs
typedef __attribute__((ext_vector_type(4))) float f32x4;

__device__ __forceinline__ unsigned short f2bfbits(float f) {
    unsigned int u = __float_as_uint(f);
    unsigned int r = (u + 0x7FFFu + ((u >> 16) & 1u)) >> 16;
    return (unsigned short)r;
}
__device__ __forceinline__ float bf2f(unsigned short b) {
    return __uint_as_float(((unsigned int)b) << 16);
}

// async global->LDS, 16B per lane. lptr must be wave-uniform; HW adds lane*16.
__device__ __forceinline__ void gload_lds16(const void* g, void* l) {
    __builtin_amdgcn_global_load_lds(
        (const __attribute__((address_space(1))) unsigned int*)g,
        (__attribute__((address_space(3))) unsigned int*)l,
        16, 0, 0);
}

// ---------------- fp32 -> bf16 elementwise (x) ----------------
__global__ __launch_bounds__(256) void cvt_f32_bf16_v4(
        const float4* __restrict__ in, ushort4* __restrict__ out, int n4) {
    int i = blockIdx.x * 256 + threadIdx.x;
    if (i < n4) {
        float4 v = in[i];
        ushort4 o;
        o.x = f2bfbits(v.x); o.y = f2bfbits(v.y);
        o.z = f2bfbits(v.z); o.w = f2bfbits(v.w);
        out[i] = o;
    }
}

// ---------------- fp32 W[K][N] -> bf16 Wt[N][K] (convert + transpose) ----------------
__global__ __launch_bounds__(256) void transcvt(
        const float* __restrict__ in, unsigned short* __restrict__ out, int K, int N) {
    __shared__ float tile[32][33];
    int kb = blockIdx.x * 32, nb = blockIdx.y * 32;
    int tx = threadIdx.x & 31, ty = threadIdx.x >> 5;   // ty: 0..7
    #pragma unroll
    for (int r = ty; r < 32; r += 8)
        tile[r][tx] = in[(size_t)(kb + r) * N + nb + tx];
    __syncthreads();
    #pragma unroll
    for (int r = ty; r < 32; r += 8)
        out[(size_t)(nb + r) * K + kb + tx] = f2bfbits(tile[tx][r]);
}

// ---------------- bf16 NT-GEMM: C[M][N] = A[M][K] * Bt[N][K]^T (+bias) ----------------
// Tile 128 x (32*NF*... BN=32*NF), BK=32, 4 waves (2x2).
// Wave covers 64 rows x (16*NF) cols = 4 x NF frags of 16x16x32.
// Staging via global_load_lds width=16 into LINEAR LDS [rows][32] bf16 (m97 pattern).
template<int NF, bool OUT_BF16, bool BIAS>
__global__ __launch_bounds__(256) void gemm_nt(
        const unsigned short* __restrict__ A,
        const unsigned short* __restrict__ Bt,
        const float* __restrict__ bias,
        void* __restrict__ C,
        int M, int N, int K) {
    constexpr int BN = 32 * NF;          // 64 or 128
    constexpr int BI = NF / 2;           // B-stage issues per wave: 1 or 2
    __shared__ __align__(16) unsigned short As[128 * 32];
    __shared__ __align__(16) unsigned short Bs[BN * 32];

    const int bm = blockIdx.x * 128;
    const int bn = blockIdx.y * BN;
    const int tid  = threadIdx.x;
    const int lane = tid & 63;
    const int wave = tid >> 6;
    const int wr = wave >> 1;            // 0..1 (64 rows each)
    const int wc = wave & 1;             // 0..1 (BN/2 cols each)
    const int fr = lane & 15;
    const int fg = lane >> 4;            // k-group 0..3

    // staging chunk geometry: chunk = 16 rows x 32 cols = 1024B = 64 lanes x 16B
    const int srow = lane >> 2;          // row within chunk
    const int scol = (lane & 3) * 8;     // col (elements)

    // A: 8 chunks, wave w handles chunks {2w, 2w+1}
    const unsigned short* agp0 = A + (size_t)(bm + wave * 32 + srow) * K + scol;
    const unsigned short* agp1 = agp0 + (size_t)16 * K;
    unsigned short* alp0 = &As[(wave * 2) * 512];
    unsigned short* alp1 = alp0 + 512;

    // B: BN/16 chunks, wave w handles chunks {w*BI .. w*BI+BI-1}
    const unsigned short* bgp[BI];
    unsigned short* blp[BI];
    #pragma unroll
    for (int r = 0; r < BI; ++r) {
        int ch = wave * BI + r;
        bgp[r] = Bt + (size_t)(bn + ch * 16 + srow) * K + scol;
        blp[r] = &Bs[ch * 512];
    }

    f32x4 acc[4][NF];
    #pragma unroll
    for (int mi = 0; mi < 4; ++mi)
        #pragma unroll
        for (int ni = 0; ni < NF; ++ni)
            acc[mi][ni] = (f32x4)(0.f);

    const int kTiles = K >> 5;
    for (int kt = 0; kt < kTiles; ++kt) {
        const int ko = kt << 5;
        gload_lds16(agp0 + ko, alp0);
        gload_lds16(agp1 + ko, alp1);
        #pragma unroll
        for (int r = 0; r < BI; ++r)
            gload_lds16(bgp[r] + ko, blp[r]);
        __syncthreads();   // drains vmcnt before barrier -> staged data visible

        frag8 a[4], b[NF];
        #pragma unroll
        for (int mi = 0; mi < 4; ++mi)
            a[mi] = *(const frag8*)&As[(wr * 64 + mi * 16 + fr) * 32 + fg * 8];
        #pragma unroll
        for (int ni = 0; ni < NF; ++ni)
            b[ni] = *(const frag8*)&Bs[(wc * (BN / 2) + ni * 16 + fr) * 32 + fg * 8];

        #pragma unroll
        for (int mi = 0; mi < 4; ++mi)
            #pragma unroll
            for (int ni = 0; ni < NF; ++ni)
                acc[mi][ni] = __builtin_amdgcn_mfma_f32_16x16x32_bf16(
                        a[mi], b[ni], acc[mi][ni], 0, 0, 0);
        __syncthreads();
    }

    // epilogue: C/D layout col=lane&15, row=(lane>>4)*4+reg  [HW-verified m89/m91]
    #pragma unroll
    for (int mi = 0; mi < 4; ++mi) {
        int grow = bm + wr * 64 + mi * 16 + fg * 4;
        #pragma unroll
        for (int ni = 0; ni < NF; ++ni) {
            int gcol = bn + wc * (BN / 2) + ni * 16 + fr;
            float bv = BIAS ? bias[gcol] : 0.f;
            #pragma unroll
            for (int r = 0; r < 4; ++r) {
                float v = acc[mi][ni][r] + bv;
                if (OUT_BF16)
                    ((unsigned short*)C)[(size_t)(grow + r) * N + gcol] = f2bfbits(v);
                else
                    ((float*)C)[(size_t)(grow + r) * N + gcol] = v;
            }
        }
    }
}

// ---------------- dilated attention: one wave per (s, head), bf16 tse ----------------
__global__ __launch_bounds__(256) void attn_kernel(
        const unsigned short* __restrict__ tse, unsigned short* __restrict__ out) {
    const int wave = threadIdx.x >> 6;
    const int lane = threadIdx.x & 63;          // = head dim index d
    const int pair = blockIdx.x * 4 + wave;     // 0 .. 32767
    const int s = pair >> 3;
    const int h = pair & 7;

    const float qd = bf2f(tse[(size_t)s * TSE_DIM + h * H_DIM + lane]);
    const float scale = 0.125f;  // 64^-0.5

    float sc[7];
    #pragma unroll
    for (int j = 0; j < 7; ++j) {
        int t = s + (j - 3) * 8;
        bool valid = (t >= 0) && (t < S_LEN);
        float p = 0.f;
        if (valid) {
            float kd = bf2f(tse[(size_t)t * TSE_DIM + D_DIM + h * H_DIM + lane]);
            p = qd * kd;
        }
        #pragma unroll
        for (int off = 32; off; off >>= 1) p += __shfl_xor(p, off, 64);
        sc[j] = valid ? p * scale : -__builtin_inff();
    }

    float m = sc[0];
    #pragma unroll
    for (int j = 1; j < 7; ++j) m = fmaxf(m, sc[j]);

    float denom = 0.f, o = 0.f;
    #pragma unroll
    for (int j = 0; j < 7; ++j) {
        int t = s + (j - 3) * 8;
        bool valid = (t >= 0) && (t < S_LEN);
        float p = valid ? __expf(sc[j] - m) : 0.f;
        denom += p;
        if (valid) {
            float vd = bf2f(tse[(size_t)t * TSE_DIM + 2 * D_DIM + h * H_DIM + lane]);
            o += p * vd;
        }
    }
    out[(size_t)s * D_DIM + h * H_DIM + lane] = f2bfbits(o / denom);
}

// ---------------- launch ----------------
extern "C" void kernel_launch(void* const* d_in, const int* in_sizes, int n_in,
                              void* d_out, int out_size, void* d_ws, size_t ws_size,
                              hipStream_t stream) {
    (void)in_sizes; (void)n_in; (void)out_size;
    const float* x     = (const float*)d_in[0];
    const float* W_in  = (const float*)d_in[1];
    const float* b_in  = (const float*)d_in[2];
    const float* W_tse = (const float*)d_in[3];
    const float* W_out = (const float*)d_in[4];
    const float* b_out = (const float*)d_in[5];

    char* p = (char*)d_ws;
    unsigned short* xb    = (unsigned short*)p; p += (size_t)S_LEN * IN_DIM * 2;
    unsigned short* WinT  = (unsigned short*)p; p += (size_t)D_DIM * IN_DIM * 2;
    unsigned short* WtseT = (unsigned short*)p; p += (size_t)TSE_DIM * D_DIM * 2;
    unsigned short* WoutT = (unsigned short*)p; p += (size_t)D_DIM * D_DIM * 2;
    unsigned short* h     = (unsigned short*)p; p += (size_t)S_LEN * D_DIM * 2;
    unsigned short* tse   = (unsigned short*)p; p += (size_t)S_LEN * TSE_DIM * 2;
    unsigned short* attn  = (unsigned short*)p; p += (size_t)S_LEN * D_DIM * 2;
    if ((size_t)(p - (char*)d_ws) > ws_size) return;

    // conversions
    cvt_f32_bf16_v4<<<(S_LEN * IN_DIM / 4 + 255) / 256, 256, 0, stream>>>(
            (const float4*)x, (ushort4*)xb, S_LEN * IN_DIM / 4);
    transcvt<<<dim3(IN_DIM / 32, D_DIM / 32), 256, 0, stream>>>(W_in, WinT, IN_DIM, D_DIM);
    transcvt<<<dim3(D_DIM / 32, TSE_DIM / 32), 256, 0, stream>>>(W_tse, WtseT, D_DIM, TSE_DIM);
    transcvt<<<dim3(D_DIM / 32, D_DIM / 32), 256, 0, stream>>>(W_out, WoutT, D_DIM, D_DIM);

    // h = x @ W_in + b_in   (bf16 out)  -- 128x64 tiles: 256 blocks = 1/CU
    gemm_nt<2, true, true><<<dim3(S_LEN / 128, D_DIM / 64), 256, 0, stream>>>(
            xb, WinT, b_in, h, S_LEN, D_DIM, IN_DIM);
    // tse = h @ W_tse       (bf16 out, no bias) -- 128x128 tiles: 384 blocks
    gemm_nt<4, true, false><<<dim3(S_LEN / 128, TSE_DIM / 128), 256, 0, stream>>>(
            h, WtseT, nullptr, tse, S_LEN, TSE_DIM, D_DIM);
    // dilated attention     (bf16 out)
    attn_kernel<<<S_LEN * N_HEADS / 4, 256, 0, stream>>>(tse, attn);
    // out = attn @ W_out + b_out  (fp32 out -> d_out)
    gemm_nt<2, false, true><<<dim3(S_LEN / 128, D_DIM / 64), 256, 0, stream>>>(
            attn, WoutT, b_out, (float*)d_out, S_LEN, D_DIM, D_DIM);
}

// Round 4
// 62.741 us; speedup vs baseline: 1.3834x; 1.3783x over previous
//
#include <hip/hip_runtime.h>
#include <hip/hip_bf16.h>

// ---------------- problem constants ----------------
#define S_LEN 4096
#define IN_DIM 768
#define D_DIM 512
#define N_HEADS 8
#define H_DIM 64
#define TSE_DIM 1536   // 3*DIM

typedef __attribute__((ext_vector_type(8))) short frag8;   // 8 bf16 = 4 VGPRs
typedef __attribute__((ext_vector_type(4))) float f32x4;

__device__ __forceinline__ unsigned short f2bfbits(float f) {
    unsigned int u = __float_as_uint(f);
    unsigned int r = (u + 0x7FFFu + ((u >> 16) & 1u)) >> 16;
    return (unsigned short)r;
}
__device__ __forceinline__ float bf2f(unsigned short b) {
    return __uint_as_float(((unsigned int)b) << 16);
}

// async global->LDS, 16B per lane. LDS dest wave-uniform; HW adds lane*16.
__device__ __forceinline__ void gload_lds16(const void* g, void* l) {
    __builtin_amdgcn_global_load_lds(
        (const __attribute__((address_space(1))) unsigned int*)g,
        (__attribute__((address_space(3))) unsigned int*)l,
        16, 0, 0);
}

// ---------------- prep: x->bf16 + 3 weight transpose-converts, one kernel ----------------
// block ranges: [0,3072) x-cvt | [3072,3456) W_in | [3456,4224) W_tse | [4224,4480) W_out
__global__ __launch_bounds__(256) void prep_kernel(
        const float4* __restrict__ x4, ushort4* __restrict__ xb4,
        const float* __restrict__ W_in,  unsigned short* __restrict__ WinT,
        const float* __restrict__ W_tse, unsigned short* __restrict__ WtseT,
        const float* __restrict__ W_out, unsigned short* __restrict__ WoutT) {
    __shared__ float tile[32][33];
    int b = blockIdx.x;
    if (b < 3072) {
        int i = b * 256 + threadIdx.x;     // n4 = 4096*768/4 = 786432 = 3072*256
        float4 v = x4[i];
        ushort4 o;
        o.x = f2bfbits(v.x); o.y = f2bfbits(v.y);
        o.z = f2bfbits(v.z); o.w = f2bfbits(v.w);
        xb4[i] = o;
        return;
    }
    const float* in; unsigned short* out; int K, N, t;
    if (b < 3456)      { t = b - 3072; in = W_in;  out = WinT;  K = IN_DIM; N = D_DIM;  }
    else if (b < 4224) { t = b - 3456; in = W_tse; out = WtseT; K = D_DIM;  N = TSE_DIM;}
    else               { t = b - 4224; in = W_out; out = WoutT; K = D_DIM;  N = D_DIM;  }
    int ktiles = K / 32;
    int kb = (t % ktiles) * 32, nb = (t / ktiles) * 32;
    int tx = threadIdx.x & 31, ty = threadIdx.x >> 5;
    #pragma unroll
    for (int r = ty; r < 32; r += 8)
        tile[r][tx] = in[(size_t)(kb + r) * N + nb + tx];
    __syncthreads();
    #pragma unroll
    for (int r = ty; r < 32; r += 8)
        out[(size_t)(nb + r) * K + kb + tx] = f2bfbits(tile[tx][r]);
}

// ---------------- bf16 NT-GEMM: C[M][N] = A[M][K] * Bt[N][K]^T (+bias) ----------------
// Tile 128 x BN (BN=32*NF), BK=32, 4 waves (2x2), global_load_lds w16, linear LDS.
template<int NF, bool OUT_BF16, bool BIAS>
__global__ __launch_bounds__(256) void gemm_nt(
        const unsigned short* __restrict__ A,
        const unsigned short* __restrict__ Bt,
        const float* __restrict__ bias,
        void* __restrict__ C,
        int M, int N, int K) {
    constexpr int BN = 32 * NF;          // 64 or 128
    constexpr int BI = NF / 2;           // B-stage issues per wave: 1 or 2
    __shared__ __align__(16) unsigned short As[128 * 32];
    __shared__ __align__(16) unsigned short Bs[BN * 32];

    const int bm = blockIdx.x * 128;
    const int bn = blockIdx.y * BN;
    const int tid  = threadIdx.x;
    const int lane = tid & 63;
    const int wave = tid >> 6;
    const int wr = wave >> 1;
    const int wc = wave & 1;
    const int fr = lane & 15;
    const int fg = lane >> 4;

    const int srow = lane >> 2;          // staging: chunk = 16 rows x 32 cols = 1024B
    const int scol = (lane & 3) * 8;

    const unsigned short* agp0 = A + (size_t)(bm + wave * 32 + srow) * K + scol;
    const unsigned short* agp1 = agp0 + (size_t)16 * K;
    unsigned short* alp0 = &As[(wave * 2) * 512];
    unsigned short* alp1 = alp0 + 512;

    const unsigned short* bgp[BI];
    unsigned short* blp[BI];
    #pragma unroll
    for (int r = 0; r < BI; ++r) {
        int ch = wave * BI + r;
        bgp[r] = Bt + (size_t)(bn + ch * 16 + srow) * K + scol;
        blp[r] = &Bs[ch * 512];
    }

    f32x4 acc[4][NF];
    #pragma unroll
    for (int mi = 0; mi < 4; ++mi)
        #pragma unroll
        for (int ni = 0; ni < NF; ++ni)
            acc[mi][ni] = (f32x4)(0.f);

    const int kTiles = K >> 5;
    for (int kt = 0; kt < kTiles; ++kt) {
        const int ko = kt << 5;
        gload_lds16(agp0 + ko, alp0);
        gload_lds16(agp1 + ko, alp1);
        #pragma unroll
        for (int r = 0; r < BI; ++r)
            gload_lds16(bgp[r] + ko, blp[r]);
        __syncthreads();

        frag8 a[4], b[NF];
        #pragma unroll
        for (int mi = 0; mi < 4; ++mi)
            a[mi] = *(const frag8*)&As[(wr * 64 + mi * 16 + fr) * 32 + fg * 8];
        #pragma unroll
        for (int ni = 0; ni < NF; ++ni)
            b[ni] = *(const frag8*)&Bs[(wc * (BN / 2) + ni * 16 + fr) * 32 + fg * 8];

        #pragma unroll
        for (int mi = 0; mi < 4; ++mi)
            #pragma unroll
            for (int ni = 0; ni < NF; ++ni)
                acc[mi][ni] = __builtin_amdgcn_mfma_f32_16x16x32_bf16(
                        a[mi], b[ni], acc[mi][ni], 0, 0, 0);
        __syncthreads();
    }

    // epilogue: C/D layout col=lane&15, row=(lane>>4)*4+reg  [HW-verified m89/m91]
    #pragma unroll
    for (int mi = 0; mi < 4; ++mi) {
        int grow = bm + wr * 64 + mi * 16 + fg * 4;
        #pragma unroll
        for (int ni = 0; ni < NF; ++ni) {
            int gcol = bn + wc * (BN / 2) + ni * 16 + fr;
            float bv = BIAS ? bias[gcol] : 0.f;
            #pragma unroll
            for (int r = 0; r < 4; ++r) {
                float v = acc[mi][ni][r] + bv;
                if (OUT_BF16)
                    ((unsigned short*)C)[(size_t)(grow + r) * N + gcol] = f2bfbits(v);
                else
                    ((float*)C)[(size_t)(grow + r) * N + gcol] = v;
            }
        }
    }
}

// ---------------- dilated attention v2: wave <-> s, lane = h*8 + d-chunk ----------------
// Every global access is 1024B contiguous per wave. Reduce = 3 cheap xor-shuffles
// (offsets 1/2/4, within 8-lane groups). Softmax over 7 scalars fully in-register.
__global__ __launch_bounds__(256) void attn_kernel(
        const unsigned short* __restrict__ tse, unsigned short* __restrict__ out) {
    const int s    = blockIdx.x * 4 + (threadIdx.x >> 6);
    const int lane = threadIdx.x & 63;
    const int off  = (lane >> 3) * H_DIM + (lane & 7) * 8;   // h*64 + d8*8

    float qf[8];
    {
        frag8 q = *(const frag8*)(tse + (size_t)s * TSE_DIM + off);
        #pragma unroll
        for (int i = 0; i < 8; ++i) qf[i] = bf2f((unsigned short)q[i]);
    }

    float sc[7];
    #pragma unroll
    for (int j = 0; j < 7; ++j) {
        int t = s + (j - 3) * 8;
        bool valid = (t >= 0) && (t < S_LEN);
        float p = 0.f;
        if (valid) {
            frag8 k = *(const frag8*)(tse + (size_t)t * TSE_DIM + D_DIM + off);
            #pragma unroll
            for (int i = 0; i < 8; ++i) p += qf[i] * bf2f((unsigned short)k[i]);
        }
        p += __shfl_xor(p, 1, 64);
        p += __shfl_xor(p, 2, 64);
        p += __shfl_xor(p, 4, 64);
        sc[j] = valid ? p * 0.125f : -__builtin_inff();
    }

    float m = sc[0];
    #pragma unroll
    for (int j = 1; j < 7; ++j) m = fmaxf(m, sc[j]);

    float w[7], denom = 0.f;
    #pragma unroll
    for (int j = 0; j < 7; ++j) {
        w[j] = (sc[j] == -__builtin_inff()) ? 0.f : __expf(sc[j] - m);
        denom += w[j];
    }
    const float inv = 1.f / denom;

    float of[8];
    #pragma unroll
    for (int i = 0; i < 8; ++i) of[i] = 0.f;
    #pragma unroll
    for (int j = 0; j < 7; ++j) {
        int t = s + (j - 3) * 8;
        if (t >= 0 && t < S_LEN) {
            frag8 v = *(const frag8*)(tse + (size_t)t * TSE_DIM + 2 * D_DIM + off);
            #pragma unroll
            for (int i = 0; i < 8; ++i) of[i] += w[j] * bf2f((unsigned short)v[i]);
        }
    }

    frag8 o;
    #pragma unroll
    for (int i = 0; i < 8; ++i) o[i] = (short)f2bfbits(of[i] * inv);
    *(frag8*)(out + (size_t)s * D_DIM + off) = o;
}

// ---------------- launch ----------------
extern "C" void kernel_launch(void* const* d_in, const int* in_sizes, int n_in,
                              void* d_out, int out_size, void* d_ws, size_t ws_size,
                              hipStream_t stream) {
    (void)in_sizes; (void)n_in; (void)out_size;
    const float* x     = (const float*)d_in[0];
    const float* W_in  = (const float*)d_in[1];
    const float* b_in  = (const float*)d_in[2];
    const float* W_tse = (const float*)d_in[3];
    const float* W_out = (const float*)d_in[4];
    const float* b_out = (const float*)d_in[5];

    char* p = (char*)d_ws;
    unsigned short* xb    = (unsigned short*)p; p += (size_t)S_LEN * IN_DIM * 2;
    unsigned short* WinT  = (unsigned short*)p; p += (size_t)D_DIM * IN_DIM * 2;
    unsigned short* WtseT = (unsigned short*)p; p += (size_t)TSE_DIM * D_DIM * 2;
    unsigned short* WoutT = (unsigned short*)p; p += (size_t)D_DIM * D_DIM * 2;
    unsigned short* h     = (unsigned short*)p; p += (size_t)S_LEN * D_DIM * 2;
    unsigned short* tse   = (unsigned short*)p; p += (size_t)S_LEN * TSE_DIM * 2;
    unsigned short* attn  = (unsigned short*)p; p += (size_t)S_LEN * D_DIM * 2;
    if ((size_t)(p - (char*)d_ws) > ws_size) return;

    // all conversions in one kernel: 3072 + 384 + 768 + 256 = 4480 blocks
    prep_kernel<<<4480, 256, 0, stream>>>(
            (const float4*)x, (ushort4*)xb, W_in, WinT, W_tse, WtseT, W_out, WoutT);

    // h = x @ W_in + b_in   (bf16 out)
    gemm_nt<2, true, true><<<dim3(S_LEN / 128, D_DIM / 64), 256, 0, stream>>>(
            xb, WinT, b_in, h, S_LEN, D_DIM, IN_DIM);
    // tse = h @ W_tse       (bf16 out, no bias)
    gemm_nt<4, true, false><<<dim3(S_LEN / 128, TSE_DIM / 128), 256, 0, stream>>>(
            h, WtseT, nullptr, tse, S_LEN, TSE_DIM, D_DIM);
    // dilated attention     (bf16 out), wave per s
    attn_kernel<<<S_LEN / 4, 256, 0, stream>>>(tse, attn);
    // out = attn @ W_out + b_out  (fp32 out -> d_out)
    gemm_nt<2, false, true><<<dim3(S_LEN / 128, D_DIM / 64), 256, 0, stream>>>(
            attn, WoutT, b_out, (float*)d_out, S_LEN, D_DIM, D_DIM);
}

// Round 5
// 53.030 us; speedup vs baseline: 1.6368x; 1.1831x over previous
//
#include <hip/hip_runtime.h>
#include <hip/hip_bf16.h>

// ---------------- problem constants ----------------
#define S_LEN 4096
#define IN_DIM 768
#define D_DIM 512
#define N_HEADS 8
#define H_DIM 64
#define TSE_DIM 1536   // 3*DIM

typedef __attribute__((ext_vector_type(8))) short frag8;   // 8 bf16 = 4 VGPRs
typedef __attribute__((ext_vector_type(4))) float f32x4;

__device__ __forceinline__ unsigned short f2bfbits(float f) {
    unsigned int u = __float_as_uint(f);
    unsigned int r = (u + 0x7FFFu + ((u >> 16) & 1u)) >> 16;
    return (unsigned short)r;
}
__device__ __forceinline__ float bf2f(unsigned short b) {
    return __uint_as_float(((unsigned int)b) << 16);
}

// async global->LDS, 16B per lane. LDS dest wave-uniform; HW adds lane*16.
__device__ __forceinline__ void gload_lds16(const void* g, void* l) {
    __builtin_amdgcn_global_load_lds(
        (const __attribute__((address_space(1))) unsigned int*)g,
        (__attribute__((address_space(3))) unsigned int*)l,
        16, 0, 0);
}

// ---------------- prep: x->bf16 + 3 weight transpose-converts, one kernel ----------------
// block ranges: [0,3072) x-cvt | [3072,3456) W_in | [3456,4224) W_tse | [4224,4480) W_out
__global__ __launch_bounds__(256) void prep_kernel(
        const float4* __restrict__ x4, ushort4* __restrict__ xb4,
        const float* __restrict__ W_in,  unsigned short* __restrict__ WinT,
        const float* __restrict__ W_tse, unsigned short* __restrict__ WtseT,
        const float* __restrict__ W_out, unsigned short* __restrict__ WoutT) {
    __shared__ float tile[32][33];
    int b = blockIdx.x;
    if (b < 3072) {
        int i = b * 256 + threadIdx.x;     // n4 = 4096*768/4 = 786432 = 3072*256
        float4 v = x4[i];
        ushort4 o;
        o.x = f2bfbits(v.x); o.y = f2bfbits(v.y);
        o.z = f2bfbits(v.z); o.w = f2bfbits(v.w);
        xb4[i] = o;
        return;
    }
    const float* in; unsigned short* out; int K, N, t;
    if (b < 3456)      { t = b - 3072; in = W_in;  out = WinT;  K = IN_DIM; N = D_DIM;  }
    else if (b < 4224) { t = b - 3456; in = W_tse; out = WtseT; K = D_DIM;  N = TSE_DIM;}
    else               { t = b - 4224; in = W_out; out = WoutT; K = D_DIM;  N = D_DIM;  }
    int ktiles = K / 32;
    int kb = (t % ktiles) * 32, nb = (t / ktiles) * 32;
    int tx = threadIdx.x & 31, ty = threadIdx.x >> 5;
    #pragma unroll
    for (int r = ty; r < 32; r += 8)
        tile[r][tx] = in[(size_t)(kb + r) * N + nb + tx];
    __syncthreads();
    #pragma unroll
    for (int r = ty; r < 32; r += 8)
        out[(size_t)(nb + r) * K + kb + tx] = f2bfbits(tile[tx][r]);
}

// ---------------- bf16 NT-GEMM, 64x64 tile, 2-phase double-buffered ----------------
// C[M][N] = A[M][K] * Bt[N][K]^T (+bias). BK=32, 4 waves (2x2), wave = 32x32 = 2x2 frags.
// Staging: global_load_lds w16, linear LDS chunks (16 rows x 32 cols = 1024B / wave).
template<bool OUT_BF16, bool BIAS>
__global__ __launch_bounds__(256) void gemm_nt(
        const unsigned short* __restrict__ A,
        const unsigned short* __restrict__ Bt,
        const float* __restrict__ bias,
        void* __restrict__ C,
        int M, int N, int K) {
    __shared__ __align__(16) unsigned short As[2][64 * 32];
    __shared__ __align__(16) unsigned short Bs[2][64 * 32];

    const int bm = blockIdx.x * 64;
    const int bn = blockIdx.y * 64;
    const int lane = threadIdx.x & 63;
    const int wave = threadIdx.x >> 6;
    const int wr = wave >> 1;            // 0..1 (32 rows each)
    const int wc = wave & 1;             // 0..1 (32 cols each)
    const int fr = lane & 15;
    const int fg = lane >> 4;            // k-group 0..3

    const int srow = lane >> 2;          // staging row within 16-row chunk
    const int scol = (lane & 3) * 8;

    // wave w stages A-chunk w and B-chunk w (rows [16w,16w+16) of each tile)
    const unsigned short* agp = A  + (size_t)(bm + wave * 16 + srow) * K + scol;
    const unsigned short* bgp = Bt + (size_t)(bn + wave * 16 + srow) * K + scol;
    unsigned short* alp0 = &As[0][wave * 512];
    unsigned short* blp0 = &Bs[0][wave * 512];
    unsigned short* alp1 = &As[1][wave * 512];
    unsigned short* blp1 = &Bs[1][wave * 512];

    f32x4 acc[2][2];
    #pragma unroll
    for (int mi = 0; mi < 2; ++mi)
        #pragma unroll
        for (int ni = 0; ni < 2; ++ni)
            acc[mi][ni] = (f32x4)(0.f);

    const int nt = K >> 5;

    // prologue: stage tile 0 into buf 0
    gload_lds16(agp, alp0);
    gload_lds16(bgp, blp0);
    __syncthreads();                      // vmcnt(0) drain + barrier

    int cur = 0;
    for (int kt = 0; kt + 1 < nt; ++kt) {
        // issue next tile's loads into the other buffer (in flight during compute)
        const int ko = (kt + 1) << 5;
        gload_lds16(agp + ko, cur ? alp0 : alp1);
        gload_lds16(bgp + ko, cur ? blp0 : blp1);

        // compute current buffer
        frag8 a[2], b[2];
        #pragma unroll
        for (int mi = 0; mi < 2; ++mi)
            a[mi] = *(const frag8*)&As[cur][(wr * 32 + mi * 16 + fr) * 32 + fg * 8];
        #pragma unroll
        for (int ni = 0; ni < 2; ++ni)
            b[ni] = *(const frag8*)&Bs[cur][(wc * 32 + ni * 16 + fr) * 32 + fg * 8];
        #pragma unroll
        for (int mi = 0; mi < 2; ++mi)
            #pragma unroll
            for (int ni = 0; ni < 2; ++ni)
                acc[mi][ni] = __builtin_amdgcn_mfma_f32_16x16x32_bf16(
                        a[mi], b[ni], acc[mi][ni], 0, 0, 0);

        __syncthreads();                  // staged data for kt+1 now visible
        cur ^= 1;
    }

    // epilogue tile (no prefetch)
    {
        frag8 a[2], b[2];
        #pragma unroll
        for (int mi = 0; mi < 2; ++mi)
            a[mi] = *(const frag8*)&As[cur][(wr * 32 + mi * 16 + fr) * 32 + fg * 8];
        #pragma unroll
        for (int ni = 0; ni < 2; ++ni)
            b[ni] = *(const frag8*)&Bs[cur][(wc * 32 + ni * 16 + fr) * 32 + fg * 8];
        #pragma unroll
        for (int mi = 0; mi < 2; ++mi)
            #pragma unroll
            for (int ni = 0; ni < 2; ++ni)
                acc[mi][ni] = __builtin_amdgcn_mfma_f32_16x16x32_bf16(
                        a[mi], b[ni], acc[mi][ni], 0, 0, 0);
    }

    // epilogue: C/D layout col=lane&15, row=(lane>>4)*4+reg  [HW-verified m89/m91]
    #pragma unroll
    for (int mi = 0; mi < 2; ++mi) {
        int grow = bm + wr * 32 + mi * 16 + fg * 4;
        #pragma unroll
        for (int ni = 0; ni < 2; ++ni) {
            int gcol = bn + wc * 32 + ni * 16 + fr;
            float bv = BIAS ? bias[gcol] : 0.f;
            #pragma unroll
            for (int r = 0; r < 4; ++r) {
                float v = acc[mi][ni][r] + bv;
                if (OUT_BF16)
                    ((unsigned short*)C)[(size_t)(grow + r) * N + gcol] = f2bfbits(v);
                else
                    ((float*)C)[(size_t)(grow + r) * N + gcol] = v;
            }
        }
    }
}

// ---------------- dilated attention: wave <-> s, lane = h*8 + d-chunk ----------------
__global__ __launch_bounds__(256) void attn_kernel(
        const unsigned short* __restrict__ tse, unsigned short* __restrict__ out) {
    const int s    = blockIdx.x * 4 + (threadIdx.x >> 6);
    const int lane = threadIdx.x & 63;
    const int off  = (lane >> 3) * H_DIM + (lane & 7) * 8;   // h*64 + d8*8

    float qf[8];
    {
        frag8 q = *(const frag8*)(tse + (size_t)s * TSE_DIM + off);
        #pragma unroll
        for (int i = 0; i < 8; ++i) qf[i] = bf2f((unsigned short)q[i]);
    }

    float sc[7];
    #pragma unroll
    for (int j = 0; j < 7; ++j) {
        int t = s + (j - 3) * 8;
        bool valid = (t >= 0) && (t < S_LEN);
        float p = 0.f;
        if (valid) {
            frag8 k = *(const frag8*)(tse + (size_t)t * TSE_DIM + D_DIM + off);
            #pragma unroll
            for (int i = 0; i < 8; ++i) p += qf[i] * bf2f((unsigned short)k[i]);
        }
        p += __shfl_xor(p, 1, 64);
        p += __shfl_xor(p, 2, 64);
        p += __shfl_xor(p, 4, 64);
        sc[j] = valid ? p * 0.125f : -__builtin_inff();
    }

    float m = sc[0];
    #pragma unroll
    for (int j = 1; j < 7; ++j) m = fmaxf(m, sc[j]);

    float w[7], denom = 0.f;
    #pragma unroll
    for (int j = 0; j < 7; ++j) {
        w[j] = (sc[j] == -__builtin_inff()) ? 0.f : __expf(sc[j] - m);
        denom += w[j];
    }
    const float inv = 1.f / denom;

    float of[8];
    #pragma unroll
    for (int i = 0; i < 8; ++i) of[i] = 0.f;
    #pragma unroll
    for (int j = 0; j < 7; ++j) {
        int t = s + (j - 3) * 8;
        if (t >= 0 && t < S_LEN) {
            frag8 v = *(const frag8*)(tse + (size_t)t * TSE_DIM + 2 * D_DIM + off);
            #pragma unroll
            for (int i = 0; i < 8; ++i) of[i] += w[j] * bf2f((unsigned short)v[i]);
        }
    }

    frag8 o;
    #pragma unroll
    for (int i = 0; i < 8; ++i) o[i] = (short)f2bfbits(of[i] * inv);
    *(frag8*)(out + (size_t)s * D_DIM + off) = o;
}

// ---------------- launch ----------------
extern "C" void kernel_launch(void* const* d_in, const int* in_sizes, int n_in,
                              void* d_out, int out_size, void* d_ws, size_t ws_size,
                              hipStream_t stream) {
    (void)in_sizes; (void)n_in; (void)out_size;
    const float* x     = (const float*)d_in[0];
    const float* W_in  = (const float*)d_in[1];
    const float* b_in  = (const float*)d_in[2];
    const float* W_tse = (const float*)d_in[3];
    const float* W_out = (const float*)d_in[4];
    const float* b_out = (const float*)d_in[5];

    char* p = (char*)d_ws;
    unsigned short* xb    = (unsigned short*)p; p += (size_t)S_LEN * IN_DIM * 2;
    unsigned short* WinT  = (unsigned short*)p; p += (size_t)D_DIM * IN_DIM * 2;
    unsigned short* WtseT = (unsigned short*)p; p += (size_t)TSE_DIM * D_DIM * 2;
    unsigned short* WoutT = (unsigned short*)p; p += (size_t)D_DIM * D_DIM * 2;
    unsigned short* h     = (unsigned short*)p; p += (size_t)S_LEN * D_DIM * 2;
    unsigned short* tse   = (unsigned short*)p; p += (size_t)S_LEN * TSE_DIM * 2;
    unsigned short* attn  = (unsigned short*)p; p += (size_t)S_LEN * D_DIM * 2;
    if ((size_t)(p - (char*)d_ws) > ws_size) return;

    // all conversions in one kernel: 3072 + 384 + 768 + 256 = 4480 blocks
    prep_kernel<<<4480, 256, 0, stream>>>(
            (const float4*)x, (ushort4*)xb, W_in, WinT, W_tse, WtseT, W_out, WoutT);

    // h = x @ W_in + b_in   (bf16 out)  -- grid (64,8) = 512 blocks
    gemm_nt<true, true><<<dim3(S_LEN / 64, D_DIM / 64), 256, 0, stream>>>(
            xb, WinT, b_in, h, S_LEN, D_DIM, IN_DIM);
    // tse = h @ W_tse       (bf16 out)  -- grid (64,24) = 1536 blocks
    gemm_nt<true, false><<<dim3(S_LEN / 64, TSE_DIM / 64), 256, 0, stream>>>(
            h, WtseT, nullptr, tse, S_LEN, TSE_DIM, D_DIM);
    // dilated attention     (bf16 out), wave per s
    attn_kernel<<<S_LEN / 4, 256, 0, stream>>>(tse, attn);
    // out = attn @ W_out + b_out  (fp32 out -> d_out)  -- grid (64,8) = 512 blocks
    gemm_nt<false, true><<<dim3(S_LEN / 64, D_DIM / 64), 256, 0, stream>>>(
            attn, WoutT, b_out, (float*)d_out, S_LEN, D_DIM, D_DIM);
}